// Round 13
// baseline (650.530 us; speedup 1.0000x reference)
//
#include <hip/hip_runtime.h>
#include <hip/hip_bf16.h>

// B=2,H=16,S=2048,D=64 fp32 attention returning (output, attention).
// v14 = v12 REVERT (best: 628.9us; fragment-major ws, barrier-free direct-
//     global pass 1, v8 staged pass 2 with bf16 Pb pair-tile + 512B nt flush)
//     + ONE micro-change: pass 2 reads the key-padding mask DIRECT from global
//     (same int4 per quad-row, L1-broadcast) instead of staging via LDS -
//     the exact pattern already validated in v12's winning pass 1. Removes the
//     divergent if(tid<64) staging store and a per-cb LDS read. Numerically
//     identical (same int32 values, same selects) -> absmax 0.0004882812.
//     v13's pass-2 direct-global K/V frags REVERTED (each wave re-read full
//     8KB K + 8KB V per tile: 64KB/block-tile vs 16KB staged -> -16us).

#define S_LEN 2048
#define D_DIM 64
#define BM 64
#define BN 64
#define NT (S_LEN / BN)   // 32 key tiles (even -> 16 pairs)
#define LDP 72            // bf16 row stride for K/Q/V LDS tiles (144 B)
#define PSTR 136          // bf16 row stride for P pair-tile (272 B, 16B-aligned)
#define BH_N 32
#define TILE_USH 4096     // ushorts per fragment-major 64x64 bf16 tile

typedef __attribute__((ext_vector_type(8))) short bf16x8;
typedef __attribute__((ext_vector_type(4))) float f32x4;

__device__ __forceinline__ unsigned pack_bf16(float a, float b) {
    union { __hip_bfloat162 h; unsigned u; } cv;
    cv.h = __float22bfloat162_rn(make_float2(a, b));   // v_cvt_pk_bf16_f32
    return cv.u;
}
__device__ __forceinline__ unsigned short bf1(float x) {
    union { __hip_bfloat16 h; unsigned short u; } cv;
    cv.h = __float2bfloat16(x);
    return cv.u;
}
__device__ __forceinline__ float bf2f(unsigned bits) {
    return __uint_as_float(bits);
}

// ---- prepass: K fp32 [bh][key][d] -> bf16 fragment-major tiles ----
// chunk c = cb*128 + ks*64 + quad*16 + l15 holds K[kt*64+cb*16+l15][ks*32+quad*8 ..+8]
__global__ __launch_bounds__(256)
void conv_k(const float* __restrict__ Kg, unsigned short* __restrict__ Kw) {
    const int kt = blockIdx.x;   // 0..31
    const int bh = blockIdx.y;   // 0..31
    const int tid = threadIdx.x;
    const float* Kb = Kg + ((size_t)bh * S_LEN + kt * 64) * D_DIM;
    unsigned short* Ko = Kw + ((size_t)bh * NT + kt) * TILE_USH;
    #pragma unroll
    for (int i = 0; i < 2; ++i) {
        int c = tid + i * 256;
        int l15 = c & 15, quad = (c >> 4) & 3, ks = (c >> 6) & 1, cb = (c >> 7) & 3;
        const float* src = Kb + (cb * 16 + l15) * D_DIM + ks * 32 + quad * 8;
        const float4 a = *(const float4*)src;
        const float4 b = *(const float4*)(src + 4);
        uint4 o;
        o.x = pack_bf16(a.x, a.y);
        o.y = pack_bf16(a.z, a.w);
        o.z = pack_bf16(b.x, b.y);
        o.w = pack_bf16(b.z, b.w);
        *(uint4*)(Ko + (size_t)c * 8) = o;   // contiguous 16B writes
    }
}

// ---- prepass: V fp32 [bh][key][d] -> bf16 V^T fragment-major tiles ----
// chunk c = db*128 + ks2*64 + quad*16 + l15 holds V^T[db*16+l15][kt*64+ks2*32+quad*8 ..+8]
__global__ __launch_bounds__(256)
void conv_vt(const float* __restrict__ Vg, unsigned short* __restrict__ Vtw) {
    const int bh = blockIdx.y;
    const int d  = threadIdx.x & 63;
    const int kq = threadIdx.x >> 6;            // 0..3
    const int key0 = blockIdx.x * 32 + kq * 8;  // multiple of 8
    const float* Vb = Vg + ((size_t)bh * S_LEN + key0) * D_DIM + d;
    float f[8];
    #pragma unroll
    for (int i = 0; i < 8; ++i) f[i] = Vb[i * D_DIM];   // coalesced across d
    uint4 o;
    o.x = pack_bf16(f[0], f[1]);
    o.y = pack_bf16(f[2], f[3]);
    o.z = pack_bf16(f[4], f[5]);
    o.w = pack_bf16(f[6], f[7]);
    const int kt  = key0 >> 6;
    const int ko  = key0 & 63;
    const int ks2 = ko >> 5, quad = (ko >> 3) & 3;
    const int db  = d >> 4,  l15  = d & 15;
    const int c   = db * 128 + ks2 * 64 + quad * 16 + l15;
    *(uint4*)(Vtw + ((size_t)bh * NT + kt) * TILE_USH + (size_t)c * 8) = o;
}

// PRE=1: fragment-major workspace (pass1 direct-global, pass2 staged, mask direct).
// PRE=0: fallback, convert in-kernel from fp32 (v8 path, mask via LDS).
template <int PRE>
__global__ __launch_bounds__(256, 4)
void attn_kernel(const float* __restrict__ Qg, const float* __restrict__ Kg,
                 const float* __restrict__ Vg, const int* __restrict__ Mg,
                 const unsigned short* __restrict__ Kw,
                 const unsigned short* __restrict__ Vtw,
                 float* __restrict__ Og, float* __restrict__ Ag) {
    __shared__ unsigned short Ks[BN * LDP];      // 9216 B  K tile [key][d]
    __shared__ unsigned short QV[D_DIM * LDP];   // 9216 B  Q tile, then V^T tile
    __shared__ unsigned short Pb[BM * PSTR];     // 17408 B bf16 P pair-tile
    __shared__ int maskS[BN];

    const int tid  = threadIdx.x;
    const int w    = tid >> 6;
    const int lane = tid & 63;
    const int l15  = lane & 15;
    const int quad = lane >> 4;

    const int qt = blockIdx.x;
    const int bh = blockIdx.y;
    const int b  = bh >> 4;
    const int q0 = qt * BM;
    const int qrow = w * 16 + l15;     // this lane's q row within the tile

    const float* Qb = Qg + ((size_t)bh * S_LEN + q0) * D_DIM;
    const int*   Mb = Mg + (size_t)b * S_LEN;
    float* Ob = Og + ((size_t)bh * S_LEN + q0) * D_DIM;
    float* Ab = Ag + ((size_t)bh * S_LEN + q0) * (size_t)S_LEN;

    // ---- stage Q scaled by log2(e)/32 (folds temperature AND exp->exp2) ----
    {
        const float sc = 0.04508422f;  // log2(e)/32
        #pragma unroll
        for (int i = 0; i < 4; ++i) {
            int f = tid + i * 256;
            int row = f >> 4, c4 = f & 15;
            const float4 v = *(const float4*)(Qb + row * D_DIM + c4 * 4);
            *(uint2*)(&QV[row * LDP + c4 * 4]) =
                make_uint2(pack_bf16(v.x * sc, v.y * sc), pack_bf16(v.z * sc, v.w * sc));
        }
    }
    __syncthreads();

    // Q fragment, reused every tile in both passes (B-operand of swapped MFMA).
    bf16x8 aq[2];
    #pragma unroll
    for (int ks = 0; ks < 2; ++ks)
        aq[ks] = *(const bf16x8*)(&QV[qrow * LDP + ks * 32 + quad * 8]);

    auto stage_k = [&](int key0) {
        if constexpr (PRE) {
            // un-permute fragment-major tile into the padded row-major LDS tile
            const unsigned short* Kt = Kw + ((size_t)bh * NT + (key0 >> 6)) * TILE_USH;
            #pragma unroll
            for (int i = 0; i < 2; ++i) {
                int c = tid + i * 256;                 // contiguous 16B reads
                uint4 vv = *(const uint4*)(Kt + (size_t)c * 8);
                int l15c = c & 15, quadc = (c >> 4) & 3, ksc = (c >> 6) & 1, cbc = (c >> 7) & 3;
                *(uint4*)(&Ks[(cbc * 16 + l15c) * LDP + ksc * 32 + quadc * 8]) = vv;
            }
        } else {
            const float* Kb = Kg + ((size_t)bh * S_LEN + key0) * D_DIM;
            #pragma unroll
            for (int i = 0; i < 4; ++i) {
                int f = tid + i * 256;
                int row = f >> 4, c4 = f & 15;
                const float4 v = *(const float4*)(Kb + row * D_DIM + c4 * 4);
                *(uint2*)(&Ks[row * LDP + c4 * 4]) =
                    make_uint2(pack_bf16(v.x, v.y), pack_bf16(v.z, v.w));
            }
        }
    };
    auto stage_v = [&](int key0) {
        if constexpr (PRE) {
            const unsigned short* Vt = Vtw + ((size_t)bh * NT + (key0 >> 6)) * TILE_USH;
            #pragma unroll
            for (int i = 0; i < 2; ++i) {
                int c = tid + i * 256;
                uint4 vv = *(const uint4*)(Vt + (size_t)c * 8);
                int l15c = c & 15, quadc = (c >> 4) & 3, ks2c = (c >> 6) & 1, dbc = (c >> 7) & 3;
                *(uint4*)(&QV[(dbc * 16 + l15c) * LDP + ks2c * 32 + quadc * 8]) = vv;
            }
        } else {
            int key = tid & 63, g2 = tid >> 6;
            #pragma unroll
            for (int i = 0; i < 4; ++i) {
                int d0 = (g2 * 4 + i) * 4;
                const float4 v = *(const float4*)(Vg + ((size_t)bh * S_LEN + key0 + key) * D_DIM + d0);
                QV[(d0 + 0) * LDP + key] = bf1(v.x);
                QV[(d0 + 1) * LDP + key] = bf1(v.y);
                QV[(d0 + 2) * LDP + key] = bf1(v.z);
                QV[(d0 + 3) * LDP + key] = bf1(v.w);
            }
        }
    };

    // ================= Pass 1: row sums of exp2(s) =================
    // Swapped MFMA: acc = K_frag * Q_frag -> D[row=key=quad*4+r][col=q=l15].
    float lsum = 0.f;

    if constexpr (PRE) {
        // Direct-global fragment reads: one wave instr = 1KB contiguous.
        // No LDS, no barriers: tiles pipeline freely; L1 serves repeat waves.
        const unsigned short* Kb = Kw + (size_t)bh * NT * TILE_USH;
        for (int kt = 0; kt < NT; ++kt) {
            const unsigned short* Kt = Kb + (size_t)kt * TILE_USH + lane * 8;
            const int* Mt = Mb + kt * BN + quad * 4;
            #pragma unroll
            for (int cb = 0; cb < 4; ++cb) {
                f32x4 acc = {0.f, 0.f, 0.f, 0.f};
                #pragma unroll
                for (int ks = 0; ks < 2; ++ks) {
                    bf16x8 bk = *(const bf16x8*)(Kt + cb * 1024 + ks * 512);
                    acc = __builtin_amdgcn_mfma_f32_16x16x32_bf16(bk, aq[ks], acc, 0, 0, 0);
                }
                const int4 m4 = *(const int4*)(Mt + cb * 16);
                float e0 = m4.x ? __builtin_exp2f(acc[0]) : 0.f;
                float e1 = m4.y ? __builtin_exp2f(acc[1]) : 0.f;
                float e2 = m4.z ? __builtin_exp2f(acc[2]) : 0.f;
                float e3 = m4.w ? __builtin_exp2f(acc[3]) : 0.f;
                lsum += (e0 + e1) + (e2 + e3);
            }
        }
    } else {
        for (int kt = 0; kt < NT; ++kt) {
            const int key0 = kt * BN;
            stage_k(key0);
            if (tid < BN) maskS[tid] = Mb[key0 + tid];
            __syncthreads();
            #pragma unroll
            for (int cb = 0; cb < 4; ++cb) {
                f32x4 acc = {0.f, 0.f, 0.f, 0.f};
                #pragma unroll
                for (int ks = 0; ks < 2; ++ks) {
                    bf16x8 bk = *(const bf16x8*)(&Ks[(cb * 16 + l15) * LDP + ks * 32 + quad * 8]);
                    acc = __builtin_amdgcn_mfma_f32_16x16x32_bf16(bk, aq[ks], acc, 0, 0, 0);
                }
                const int4 m4 = *(const int4*)(&maskS[cb * 16 + quad * 4]);
                float e0 = m4.x ? __builtin_exp2f(acc[0]) : 0.f;
                float e1 = m4.y ? __builtin_exp2f(acc[1]) : 0.f;
                float e2 = m4.z ? __builtin_exp2f(acc[2]) : 0.f;
                float e3 = m4.w ? __builtin_exp2f(acc[3]) : 0.f;
                lsum += (e0 + e1) + (e2 + e3);
            }
            __syncthreads();
        }
    }

    // quads hold disjoint key subsets of the SAME q row -> 2-shuffle reduce
    lsum += __shfl_xor(lsum, 16);
    lsum += __shfl_xor(lsum, 32);
    const float linv = 1.0f / lsum;

    // All waves finished pass 1 (and aq reads) before pass 2 overwrites QV.
    __syncthreads();

    // ================= Pass 2 (= v8): pair loop, bf16 Pb, 512B nt A-flush ====
    f32x4 oacc[4];
    #pragma unroll
    for (int db = 0; db < 4; ++db) oacc[db] = (f32x4){0.f, 0.f, 0.f, 0.f};

    for (int kt2 = 0; kt2 < NT / 2; ++kt2) {
        #pragma unroll
        for (int half = 0; half < 2; ++half) {
            const int key0 = (kt2 * 2 + half) * BN;
            stage_k(key0);
            stage_v(key0);
            if constexpr (!PRE) {
                if (tid < BN) maskS[tid] = Mb[key0 + tid];
            }
            // Barrier also orders prev pair's cooperative Pb reads before this
            // half's Pb writes below.
            __syncthreads();

            // QK^T -> exp2 -> normalized bf16 P into this half's columns.
            #pragma unroll
            for (int cb = 0; cb < 4; ++cb) {
                f32x4 acc = {0.f, 0.f, 0.f, 0.f};
                #pragma unroll
                for (int ks = 0; ks < 2; ++ks) {
                    bf16x8 bk = *(const bf16x8*)(&Ks[(cb * 16 + l15) * LDP + ks * 32 + quad * 8]);
                    acc = __builtin_amdgcn_mfma_f32_16x16x32_bf16(bk, aq[ks], acc, 0, 0, 0);
                }
                int4 m4;
                if constexpr (PRE) {
                    // direct L1-broadcast read (validated pattern from pass 1)
                    m4 = *(const int4*)(Mb + key0 + cb * 16 + quad * 4);
                } else {
                    m4 = *(const int4*)(&maskS[cb * 16 + quad * 4]);
                }
                float p0 = (m4.x ? __builtin_exp2f(acc[0]) : 0.f) * linv;
                float p1 = (m4.y ? __builtin_exp2f(acc[1]) : 0.f) * linv;
                float p2 = (m4.z ? __builtin_exp2f(acc[2]) : 0.f) * linv;
                float p3 = (m4.w ? __builtin_exp2f(acc[3]) : 0.f) * linv;
                *(uint2*)(&Pb[qrow * PSTR + half * 64 + cb * 16 + quad * 4]) =
                    make_uint2(pack_bf16(p0, p1), pack_bf16(p2, p3));
            }

            // PV: A = V^T frag, B = bf16 P frag read back from this wave's OWN
            // Pb rows (same-wave RAW -> compiler lgkmcnt; same bits as cvt_pk).
            #pragma unroll
            for (int ks2 = 0; ks2 < 2; ++ks2) {
                bf16x8 ap = *(const bf16x8*)(&Pb[qrow * PSTR + half * 64 + ks2 * 32 + quad * 8]);
                #pragma unroll
                for (int db = 0; db < 4; ++db) {
                    bf16x8 bv = *(const bf16x8*)(&QV[(db * 16 + l15) * LDP + ks2 * 32 + quad * 8]);
                    oacc[db] = __builtin_amdgcn_mfma_f32_16x16x32_bf16(bv, ap, oacc[db], 0, 0, 0);
                }
            }
            __syncthreads();   // half fully written; Ks/QV reads done before restage
        }

        // Cooperative nt A-flush of the pair: 64 rows x 128 keys, per-row 512B
        // contiguous segments (16B/lane). Overlaps next pair's staging loads.
        const int key00 = kt2 * 2 * BN;
        #pragma unroll
        for (int i = 0; i < 8; ++i) {
            int idx = tid + i * 256;          // 0..2047 uint2 chunks of 4 bf16
            int row = idx >> 5, c4 = idx & 31;
            uint2 pu = *(const uint2*)(&Pb[row * PSTR + c4 * 4]);
            f32x4 t;
            t[0] = bf2f(pu.x << 16); t[1] = bf2f(pu.x & 0xffff0000u);
            t[2] = bf2f(pu.y << 16); t[3] = bf2f(pu.y & 0xffff0000u);
            __builtin_nontemporal_store(
                t, (f32x4*)(Ab + (size_t)row * S_LEN + key00 + c4 * 4));
        }
    }

    // write O: lane holds d = db*16 + quad*4 + r for row qrow -> float4 stores
    #pragma unroll
    for (int db = 0; db < 4; ++db) {
        f32x4 o4 = oacc[db];
        __builtin_nontemporal_store(
            o4, (f32x4*)(Ob + (size_t)qrow * D_DIM + db * 16 + quad * 4));
    }
}

extern "C" void kernel_launch(void* const* d_in, const int* in_sizes, int n_in,
                              void* d_out, int out_size, void* d_ws, size_t ws_size,
                              hipStream_t stream) {
    const float* q = (const float*)d_in[0];
    const float* k = (const float*)d_in[1];
    const float* v = (const float*)d_in[2];
    const int* mask = (const int*)d_in[3];
    float* out = (float*)d_out;                         // [B,H,S,D]
    float* attn = out + (size_t)2 * 16 * 2048 * 64;     // [B,H,S,S]

    const size_t kw_elems = (size_t)BH_N * S_LEN * D_DIM;        // 4.19M ushorts
    const size_t need = 2 * kw_elems * sizeof(unsigned short);   // 16.8 MB
    dim3 block(256);
    dim3 grid(S_LEN / BM, BH_N);

    if (d_ws && ws_size >= need) {
        unsigned short* Kw  = (unsigned short*)d_ws;
        unsigned short* Vtw = Kw + kw_elems;
        conv_k<<<dim3(NT, BH_N), block, 0, stream>>>(k, Kw);
        conv_vt<<<dim3(S_LEN / 32, BH_N), block, 0, stream>>>(v, Vtw);
        attn_kernel<1><<<grid, block, 0, stream>>>(q, k, v, mask, Kw, Vtw, out, attn);
    } else {
        attn_kernel<0><<<grid, block, 0, stream>>>(q, k, v, mask, nullptr, nullptr, out, attn);
    }
}

// Round 14
// 627.234 us; speedup vs baseline: 1.0371x; 1.0371x over previous
//
#include <hip/hip_runtime.h>
#include <hip/hip_bf16.h>

// B=2,H=16,S=2048,D=64 fp32 attention returning (output, attention).
// v15 = v12 VERBATIM REVERT (session best: 628.9us). Final configuration:
//     * Prepass: K -> bf16 fragment-major tiles, V -> bf16 V^T fragment-major
//       tiles in d_ws (16.8MB).
//     * Pass 1 (lsum): BARRIER-FREE direct-global K-fragment reads - one wave
//       instr = one contiguous 1KB block; no LDS, loads pipeline freely.
//     * Pass 2: v8 staged structure - K/V^T un-permuted into padded LDS tiles
//       (16KB/tile-pass shared by 4 waves; direct-global here LOSES, v13/v14),
//       mask via LDS broadcast, bf16 Pb pair-tile, PV from own Pb rows,
//       cooperative nt A-flush as 512B contiguous segments per row.
//     A/B ledger (14 rounds): nt>plain (v9), 512B>256B (v8), staged>direct in
//     pass2 (v13), LDS-mask>direct-mask (v14), barriers not the cost (v6),
//     pipelining hurts (v5), occupancy push hurts (v7), XCD pin hurts (v11),
//     kernel split hurts (v10). This is the measured practical floor.

#define S_LEN 2048
#define D_DIM 64
#define BM 64
#define BN 64
#define NT (S_LEN / BN)   // 32 key tiles (even -> 16 pairs)
#define LDP 72            // bf16 row stride for K/Q/V LDS tiles (144 B)
#define PSTR 136          // bf16 row stride for P pair-tile (272 B, 16B-aligned)
#define BH_N 32
#define TILE_USH 4096     // ushorts per fragment-major 64x64 bf16 tile

typedef __attribute__((ext_vector_type(8))) short bf16x8;
typedef __attribute__((ext_vector_type(4))) float f32x4;

__device__ __forceinline__ unsigned pack_bf16(float a, float b) {
    union { __hip_bfloat162 h; unsigned u; } cv;
    cv.h = __float22bfloat162_rn(make_float2(a, b));   // v_cvt_pk_bf16_f32
    return cv.u;
}
__device__ __forceinline__ unsigned short bf1(float x) {
    union { __hip_bfloat16 h; unsigned short u; } cv;
    cv.h = __float2bfloat16(x);
    return cv.u;
}
__device__ __forceinline__ float bf2f(unsigned bits) {
    return __uint_as_float(bits);
}

// ---- prepass: K fp32 [bh][key][d] -> bf16 fragment-major tiles ----
// chunk c = cb*128 + ks*64 + quad*16 + l15 holds K[kt*64+cb*16+l15][ks*32+quad*8 ..+8]
__global__ __launch_bounds__(256)
void conv_k(const float* __restrict__ Kg, unsigned short* __restrict__ Kw) {
    const int kt = blockIdx.x;   // 0..31
    const int bh = blockIdx.y;   // 0..31
    const int tid = threadIdx.x;
    const float* Kb = Kg + ((size_t)bh * S_LEN + kt * 64) * D_DIM;
    unsigned short* Ko = Kw + ((size_t)bh * NT + kt) * TILE_USH;
    #pragma unroll
    for (int i = 0; i < 2; ++i) {
        int c = tid + i * 256;
        int l15 = c & 15, quad = (c >> 4) & 3, ks = (c >> 6) & 1, cb = (c >> 7) & 3;
        const float* src = Kb + (cb * 16 + l15) * D_DIM + ks * 32 + quad * 8;
        const float4 a = *(const float4*)src;
        const float4 b = *(const float4*)(src + 4);
        uint4 o;
        o.x = pack_bf16(a.x, a.y);
        o.y = pack_bf16(a.z, a.w);
        o.z = pack_bf16(b.x, b.y);
        o.w = pack_bf16(b.z, b.w);
        *(uint4*)(Ko + (size_t)c * 8) = o;   // contiguous 16B writes
    }
}

// ---- prepass: V fp32 [bh][key][d] -> bf16 V^T fragment-major tiles ----
// chunk c = db*128 + ks2*64 + quad*16 + l15 holds V^T[db*16+l15][kt*64+ks2*32+quad*8 ..+8]
__global__ __launch_bounds__(256)
void conv_vt(const float* __restrict__ Vg, unsigned short* __restrict__ Vtw) {
    const int bh = blockIdx.y;
    const int d  = threadIdx.x & 63;
    const int kq = threadIdx.x >> 6;            // 0..3
    const int key0 = blockIdx.x * 32 + kq * 8;  // multiple of 8
    const float* Vb = Vg + ((size_t)bh * S_LEN + key0) * D_DIM + d;
    float f[8];
    #pragma unroll
    for (int i = 0; i < 8; ++i) f[i] = Vb[i * D_DIM];   // coalesced across d
    uint4 o;
    o.x = pack_bf16(f[0], f[1]);
    o.y = pack_bf16(f[2], f[3]);
    o.z = pack_bf16(f[4], f[5]);
    o.w = pack_bf16(f[6], f[7]);
    const int kt  = key0 >> 6;
    const int ko  = key0 & 63;
    const int ks2 = ko >> 5, quad = (ko >> 3) & 3;
    const int db  = d >> 4,  l15  = d & 15;
    const int c   = db * 128 + ks2 * 64 + quad * 16 + l15;
    *(uint4*)(Vtw + ((size_t)bh * NT + kt) * TILE_USH + (size_t)c * 8) = o;
}

// PRE=1: fragment-major workspace (pass1 direct-global, pass2 staged).
// PRE=0: fallback, convert in-kernel from fp32 (v8 path).
template <int PRE>
__global__ __launch_bounds__(256, 4)
void attn_kernel(const float* __restrict__ Qg, const float* __restrict__ Kg,
                 const float* __restrict__ Vg, const int* __restrict__ Mg,
                 const unsigned short* __restrict__ Kw,
                 const unsigned short* __restrict__ Vtw,
                 float* __restrict__ Og, float* __restrict__ Ag) {
    __shared__ unsigned short Ks[BN * LDP];      // 9216 B  K tile [key][d]
    __shared__ unsigned short QV[D_DIM * LDP];   // 9216 B  Q tile, then V^T tile
    __shared__ unsigned short Pb[BM * PSTR];     // 17408 B bf16 P pair-tile
    __shared__ int maskS[BN];

    const int tid  = threadIdx.x;
    const int w    = tid >> 6;
    const int lane = tid & 63;
    const int l15  = lane & 15;
    const int quad = lane >> 4;

    const int qt = blockIdx.x;
    const int bh = blockIdx.y;
    const int b  = bh >> 4;
    const int q0 = qt * BM;
    const int qrow = w * 16 + l15;     // this lane's q row within the tile

    const float* Qb = Qg + ((size_t)bh * S_LEN + q0) * D_DIM;
    const int*   Mb = Mg + (size_t)b * S_LEN;
    float* Ob = Og + ((size_t)bh * S_LEN + q0) * D_DIM;
    float* Ab = Ag + ((size_t)bh * S_LEN + q0) * (size_t)S_LEN;

    // ---- stage Q scaled by log2(e)/32 (folds temperature AND exp->exp2) ----
    {
        const float sc = 0.04508422f;  // log2(e)/32
        #pragma unroll
        for (int i = 0; i < 4; ++i) {
            int f = tid + i * 256;
            int row = f >> 4, c4 = f & 15;
            const float4 v = *(const float4*)(Qb + row * D_DIM + c4 * 4);
            *(uint2*)(&QV[row * LDP + c4 * 4]) =
                make_uint2(pack_bf16(v.x * sc, v.y * sc), pack_bf16(v.z * sc, v.w * sc));
        }
    }
    __syncthreads();

    // Q fragment, reused every tile in both passes (B-operand of swapped MFMA).
    bf16x8 aq[2];
    #pragma unroll
    for (int ks = 0; ks < 2; ++ks)
        aq[ks] = *(const bf16x8*)(&QV[qrow * LDP + ks * 32 + quad * 8]);

    auto stage_k = [&](int key0) {
        if constexpr (PRE) {
            // un-permute fragment-major tile into the padded row-major LDS tile
            const unsigned short* Kt = Kw + ((size_t)bh * NT + (key0 >> 6)) * TILE_USH;
            #pragma unroll
            for (int i = 0; i < 2; ++i) {
                int c = tid + i * 256;                 // contiguous 16B reads
                uint4 vv = *(const uint4*)(Kt + (size_t)c * 8);
                int l15c = c & 15, quadc = (c >> 4) & 3, ksc = (c >> 6) & 1, cbc = (c >> 7) & 3;
                *(uint4*)(&Ks[(cbc * 16 + l15c) * LDP + ksc * 32 + quadc * 8]) = vv;
            }
        } else {
            const float* Kb = Kg + ((size_t)bh * S_LEN + key0) * D_DIM;
            #pragma unroll
            for (int i = 0; i < 4; ++i) {
                int f = tid + i * 256;
                int row = f >> 4, c4 = f & 15;
                const float4 v = *(const float4*)(Kb + row * D_DIM + c4 * 4);
                *(uint2*)(&Ks[row * LDP + c4 * 4]) =
                    make_uint2(pack_bf16(v.x, v.y), pack_bf16(v.z, v.w));
            }
        }
    };
    auto stage_v = [&](int key0) {
        if constexpr (PRE) {
            const unsigned short* Vt = Vtw + ((size_t)bh * NT + (key0 >> 6)) * TILE_USH;
            #pragma unroll
            for (int i = 0; i < 2; ++i) {
                int c = tid + i * 256;
                uint4 vv = *(const uint4*)(Vt + (size_t)c * 8);
                int l15c = c & 15, quadc = (c >> 4) & 3, ks2c = (c >> 6) & 1, dbc = (c >> 7) & 3;
                *(uint4*)(&QV[(dbc * 16 + l15c) * LDP + ks2c * 32 + quadc * 8]) = vv;
            }
        } else {
            int key = tid & 63, g2 = tid >> 6;
            #pragma unroll
            for (int i = 0; i < 4; ++i) {
                int d0 = (g2 * 4 + i) * 4;
                const float4 v = *(const float4*)(Vg + ((size_t)bh * S_LEN + key0 + key) * D_DIM + d0);
                QV[(d0 + 0) * LDP + key] = bf1(v.x);
                QV[(d0 + 1) * LDP + key] = bf1(v.y);
                QV[(d0 + 2) * LDP + key] = bf1(v.z);
                QV[(d0 + 3) * LDP + key] = bf1(v.w);
            }
        }
    };

    // ================= Pass 1: row sums of exp2(s) =================
    // Swapped MFMA: acc = K_frag * Q_frag -> D[row=key=quad*4+r][col=q=l15].
    float lsum = 0.f;

    if constexpr (PRE) {
        // Direct-global fragment reads: one wave instr = 1KB contiguous.
        // No LDS, no barriers: tiles pipeline freely; L1 serves repeat waves.
        const unsigned short* Kb = Kw + (size_t)bh * NT * TILE_USH;
        for (int kt = 0; kt < NT; ++kt) {
            const unsigned short* Kt = Kb + (size_t)kt * TILE_USH + lane * 8;
            const int* Mt = Mb + kt * BN + quad * 4;
            #pragma unroll
            for (int cb = 0; cb < 4; ++cb) {
                f32x4 acc = {0.f, 0.f, 0.f, 0.f};
                #pragma unroll
                for (int ks = 0; ks < 2; ++ks) {
                    bf16x8 bk = *(const bf16x8*)(Kt + cb * 1024 + ks * 512);
                    acc = __builtin_amdgcn_mfma_f32_16x16x32_bf16(bk, aq[ks], acc, 0, 0, 0);
                }
                const int4 m4 = *(const int4*)(Mt + cb * 16);
                float e0 = m4.x ? __builtin_exp2f(acc[0]) : 0.f;
                float e1 = m4.y ? __builtin_exp2f(acc[1]) : 0.f;
                float e2 = m4.z ? __builtin_exp2f(acc[2]) : 0.f;
                float e3 = m4.w ? __builtin_exp2f(acc[3]) : 0.f;
                lsum += (e0 + e1) + (e2 + e3);
            }
        }
    } else {
        for (int kt = 0; kt < NT; ++kt) {
            const int key0 = kt * BN;
            stage_k(key0);
            if (tid < BN) maskS[tid] = Mb[key0 + tid];
            __syncthreads();
            #pragma unroll
            for (int cb = 0; cb < 4; ++cb) {
                f32x4 acc = {0.f, 0.f, 0.f, 0.f};
                #pragma unroll
                for (int ks = 0; ks < 2; ++ks) {
                    bf16x8 bk = *(const bf16x8*)(&Ks[(cb * 16 + l15) * LDP + ks * 32 + quad * 8]);
                    acc = __builtin_amdgcn_mfma_f32_16x16x32_bf16(bk, aq[ks], acc, 0, 0, 0);
                }
                const int4 m4 = *(const int4*)(&maskS[cb * 16 + quad * 4]);
                float e0 = m4.x ? __builtin_exp2f(acc[0]) : 0.f;
                float e1 = m4.y ? __builtin_exp2f(acc[1]) : 0.f;
                float e2 = m4.z ? __builtin_exp2f(acc[2]) : 0.f;
                float e3 = m4.w ? __builtin_exp2f(acc[3]) : 0.f;
                lsum += (e0 + e1) + (e2 + e3);
            }
            __syncthreads();
        }
    }

    // quads hold disjoint key subsets of the SAME q row -> 2-shuffle reduce
    lsum += __shfl_xor(lsum, 16);
    lsum += __shfl_xor(lsum, 32);
    const float linv = 1.0f / lsum;

    // All waves finished pass 1 (and aq reads) before pass 2 overwrites QV.
    __syncthreads();

    // ================= Pass 2 (= v8): pair loop, bf16 Pb, 512B nt A-flush ====
    f32x4 oacc[4];
    #pragma unroll
    for (int db = 0; db < 4; ++db) oacc[db] = (f32x4){0.f, 0.f, 0.f, 0.f};

    for (int kt2 = 0; kt2 < NT / 2; ++kt2) {
        #pragma unroll
        for (int half = 0; half < 2; ++half) {
            const int key0 = (kt2 * 2 + half) * BN;
            stage_k(key0);
            stage_v(key0);
            if (tid < BN) maskS[tid] = Mb[key0 + tid];
            // Barrier also orders prev pair's cooperative Pb reads before this
            // half's Pb writes below.
            __syncthreads();

            // QK^T -> exp2 -> normalized bf16 P into this half's columns.
            #pragma unroll
            for (int cb = 0; cb < 4; ++cb) {
                f32x4 acc = {0.f, 0.f, 0.f, 0.f};
                #pragma unroll
                for (int ks = 0; ks < 2; ++ks) {
                    bf16x8 bk = *(const bf16x8*)(&Ks[(cb * 16 + l15) * LDP + ks * 32 + quad * 8]);
                    acc = __builtin_amdgcn_mfma_f32_16x16x32_bf16(bk, aq[ks], acc, 0, 0, 0);
                }
                const int4 m4 = *(const int4*)(&maskS[cb * 16 + quad * 4]);
                float p0 = (m4.x ? __builtin_exp2f(acc[0]) : 0.f) * linv;
                float p1 = (m4.y ? __builtin_exp2f(acc[1]) : 0.f) * linv;
                float p2 = (m4.z ? __builtin_exp2f(acc[2]) : 0.f) * linv;
                float p3 = (m4.w ? __builtin_exp2f(acc[3]) : 0.f) * linv;
                *(uint2*)(&Pb[qrow * PSTR + half * 64 + cb * 16 + quad * 4]) =
                    make_uint2(pack_bf16(p0, p1), pack_bf16(p2, p3));
            }

            // PV: A = V^T frag, B = bf16 P frag read back from this wave's OWN
            // Pb rows (same-wave RAW -> compiler lgkmcnt; same bits as cvt_pk).
            #pragma unroll
            for (int ks2 = 0; ks2 < 2; ++ks2) {
                bf16x8 ap = *(const bf16x8*)(&Pb[qrow * PSTR + half * 64 + ks2 * 32 + quad * 8]);
                #pragma unroll
                for (int db = 0; db < 4; ++db) {
                    bf16x8 bv = *(const bf16x8*)(&QV[(db * 16 + l15) * LDP + ks2 * 32 + quad * 8]);
                    oacc[db] = __builtin_amdgcn_mfma_f32_16x16x32_bf16(bv, ap, oacc[db], 0, 0, 0);
                }
            }
            __syncthreads();   // half fully written; Ks/QV reads done before restage
        }

        // Cooperative nt A-flush of the pair: 64 rows x 128 keys, per-row 512B
        // contiguous segments (16B/lane). Overlaps next pair's staging loads.
        const int key00 = kt2 * 2 * BN;
        #pragma unroll
        for (int i = 0; i < 8; ++i) {
            int idx = tid + i * 256;          // 0..2047 uint2 chunks of 4 bf16
            int row = idx >> 5, c4 = idx & 31;
            uint2 pu = *(const uint2*)(&Pb[row * PSTR + c4 * 4]);
            f32x4 t;
            t[0] = bf2f(pu.x << 16); t[1] = bf2f(pu.x & 0xffff0000u);
            t[2] = bf2f(pu.y << 16); t[3] = bf2f(pu.y & 0xffff0000u);
            __builtin_nontemporal_store(
                t, (f32x4*)(Ab + (size_t)row * S_LEN + key00 + c4 * 4));
        }
    }

    // write O: lane holds d = db*16 + quad*4 + r for row qrow -> float4 stores
    #pragma unroll
    for (int db = 0; db < 4; ++db) {
        f32x4 o4 = oacc[db];
        __builtin_nontemporal_store(
            o4, (f32x4*)(Ob + (size_t)qrow * D_DIM + db * 16 + quad * 4));
    }
}

extern "C" void kernel_launch(void* const* d_in, const int* in_sizes, int n_in,
                              void* d_out, int out_size, void* d_ws, size_t ws_size,
                              hipStream_t stream) {
    const float* q = (const float*)d_in[0];
    const float* k = (const float*)d_in[1];
    const float* v = (const float*)d_in[2];
    const int* mask = (const int*)d_in[3];
    float* out = (float*)d_out;                         // [B,H,S,D]
    float* attn = out + (size_t)2 * 16 * 2048 * 64;     // [B,H,S,S]

    const size_t kw_elems = (size_t)BH_N * S_LEN * D_DIM;        // 4.19M ushorts
    const size_t need = 2 * kw_elems * sizeof(unsigned short);   // 16.8 MB
    dim3 block(256);
    dim3 grid(S_LEN / BM, BH_N);

    if (d_ws && ws_size >= need) {
        unsigned short* Kw  = (unsigned short*)d_ws;
        unsigned short* Vtw = Kw + kw_elems;
        conv_k<<<dim3(NT, BH_N), block, 0, stream>>>(k, Kw);
        conv_vt<<<dim3(S_LEN / 32, BH_N), block, 0, stream>>>(v, Vtw);
        attn_kernel<1><<<grid, block, 0, stream>>>(q, k, v, mask, Kw, Vtw, out, attn);
    } else {
        attn_kernel<0><<<grid, block, 0, stream>>>(q, k, v, mask, nullptr, nullptr, out, attn);
    }
}